// Round 5
// baseline (606.214 us; speedup 1.0000x reference)
//
#include <hip/hip_runtime.h>
#include <hip/hip_fp16.h>

// SelfAttention (B=8, C=256, H=W=64): fp16-MFMA pipeline.
// R5: k_attn restructured to 32-q-row waves + mfma_32x32x16 + swapped QK^T
// (S^T in regs -> lane-local softmax, in-register P via cvt_pkrtz+shfl,
// no P-LDS), KVBLK=32 double-buffered global_load_lds staging (pre-swizzled
// source), defer-max rescale (THR=8, log2 domain). One barrier/iteration.

using half8  = _Float16 __attribute__((ext_vector_type(8)));
using half4v = _Float16 __attribute__((ext_vector_type(4)));
using f32x4  = float    __attribute__((ext_vector_type(4)));
using f32x16 = float    __attribute__((ext_vector_type(16)));

#define HWC 1048576  // 4096*256 elements per batch

#define G2L(gp, lp)                                                   \
  __builtin_amdgcn_global_load_lds(                                   \
      (const __attribute__((address_space(1))) void*)(gp),            \
      (__attribute__((address_space(3))) void*)(lp), 16, 0, 0)

// ---------------- W fp32 -> f16 ----------------
__global__ void k_convert_w(const float* __restrict__ wq, const float* __restrict__ wk,
                            const float* __restrict__ wv, const float* __restrict__ wp,
                            _Float16* __restrict__ out) {
  int idx = (blockIdx.x * 256 + threadIdx.x) * 4;  // over 4*65536
  const float* src = idx < 65536 ? wq : idx < 131072 ? wk : idx < 196608 ? wv : wp;
  float4 v = *reinterpret_cast<const float4*>(src + (idx & 65535));
  half4v h = { (_Float16)v.x, (_Float16)v.y, (_Float16)v.z, (_Float16)v.w };
  *reinterpret_cast<half4v*>(out + idx) = h;
}

// ---------------- transpose fp32 (R,S) -> f16 (S,R), 64x64 tiles ----------------
__global__ void k_transpose_f32(const float* __restrict__ in, _Float16* __restrict__ out,
                                int R, int S) {
  size_t base = (size_t)blockIdx.z * R * S;
  in += base; out += base;
  int r0 = blockIdx.y * 64, s0 = blockIdx.x * 64;
  __shared__ _Float16 tile[4096];
  char* tb = (char*)tile;
  int t = threadIdx.x;
#pragma unroll
  for (int i = 0; i < 4; ++i) {
    int row = i * 16 + (t >> 4);
    int co  = t & 15;
    float4 v = *reinterpret_cast<const float4*>(in + (size_t)(r0 + row) * S + s0 + co * 4);
    float vv[4] = {v.x, v.y, v.z, v.w};
#pragma unroll
    for (int e = 0; e < 4; ++e) {
      int sl = co * 4 + e;
      int byte = (sl * 128 + row * 2) ^ (((sl >> 3) & 7) << 4);
      *reinterpret_cast<_Float16*>(tb + byte) = (_Float16)vv[e];
    }
  }
  __syncthreads();
#pragma unroll
  for (int i = 0; i < 2; ++i) {
    int so  = i * 32 + (t >> 3);
    int co2 = t & 7;
    int byte = (so * 128 + co2 * 16) ^ (((so >> 3) & 7) << 4);
    uint4 v = *reinterpret_cast<const uint4*>(tb + byte);
    *reinterpret_cast<uint4*>(out + (size_t)(s0 + so) * R + r0 + co2 * 8) = v;
  }
}

// ---------------- transpose f16 (R,S) -> f16 (S,R), 64x64 tiles ----------------
__global__ void k_transpose_h16(const _Float16* __restrict__ in, _Float16* __restrict__ out,
                                int R, int S) {
  size_t base = (size_t)blockIdx.z * R * S;
  in += base; out += base;
  int r0 = blockIdx.y * 64, s0 = blockIdx.x * 64;
  __shared__ _Float16 tile[4096];
  char* tb = (char*)tile;
  int t = threadIdx.x;
#pragma unroll
  for (int i = 0; i < 2; ++i) {
    int row = i * 32 + (t >> 3);
    int co  = t & 7;
    half8 v = *reinterpret_cast<const half8*>(in + (size_t)(r0 + row) * S + s0 + co * 8);
#pragma unroll
    for (int e = 0; e < 8; ++e) {
      int sl = co * 8 + e;
      int byte = (sl * 128 + row * 2) ^ (((sl >> 3) & 7) << 4);
      *reinterpret_cast<_Float16*>(tb + byte) = v[e];
    }
  }
  __syncthreads();
#pragma unroll
  for (int i = 0; i < 2; ++i) {
    int so  = i * 32 + (t >> 3);
    int co2 = t & 7;
    int byte = (so * 128 + co2 * 16) ^ (((so >> 3) & 7) << 4);
    uint4 v = *reinterpret_cast<const uint4*>(tb + byte);
    *reinterpret_cast<uint4*>(out + (size_t)(s0 + so) * R + r0 + co2 * 8) = v;
  }
}

// ---------------- GEMM: Y[M,N] = A[M,K=256] * Bt[N,K=256]^T, batched ----------------
template <bool OUT_F32>
__global__ __launch_bounds__(256) void k_gemm(const _Float16* __restrict__ A,
                                              const _Float16* __restrict__ Bt,
                                              void* __restrict__ Yv, int M, int N,
                                              long sA, long sB, long sY, float scale) {
  int b = blockIdx.z;
  A  += (size_t)b * sA;
  Bt += (size_t)b * sB;
  int n0 = blockIdx.x * 64, m0 = blockIdx.y * 64;
  int t = threadIdx.x, wave = t >> 6, lane = t & 63;
  int lm = lane & 15, lk8 = (lane >> 4) * 8;
  int nr = n0 + wave * 16 + lm;
  f32x4 zero = {0.f, 0.f, 0.f, 0.f};
  f32x4 acc[4] = {zero, zero, zero, zero};
#pragma unroll
  for (int ks = 0; ks < 8; ++ks) {
    half8 bf = *reinterpret_cast<const half8*>(Bt + (size_t)nr * 256 + ks * 32 + lk8);
#pragma unroll
    for (int mt = 0; mt < 4; ++mt) {
      half8 af = *reinterpret_cast<const half8*>(A + (size_t)(m0 + mt * 16 + lm) * 256 + ks * 32 + lk8);
      acc[mt] = __builtin_amdgcn_mfma_f32_16x16x32_f16(af, bf, acc[mt], 0, 0, 0);
    }
  }
  int rq = (lane >> 4) * 4;
#pragma unroll
  for (int mt = 0; mt < 4; ++mt) {
#pragma unroll
    for (int r = 0; r < 4; ++r) {
      size_t off = (size_t)(m0 + mt * 16 + rq + r) * N + n0 + wave * 16 + lm;
      float v = acc[mt][r] * scale;
      if (OUT_F32) reinterpret_cast<float*>(Yv)[(size_t)b * sY + off] = v;
      else reinterpret_cast<_Float16*>(Yv)[(size_t)b * sY + off] = (_Float16)v;
    }
  }
}

// ---------------- flash attention (32-q-row waves, swapped QK^T) ----------------
// Q (HW,C) f16 pre-scaled by log2e/sqrt(C); Kt (HW,C) f16; Vt (C,HW) f16; O (HW,C) f16.
// WG: 256 thr = 4 waves x 32 q-rows (q-tile 128). KVBLK=32.
// LDS: 2 buffers x (K 16KB [32 keys][256 ch] + V 16KB [256 ch][32 keys]), 64KB.
// Swapped QK^T: sacc = mfma(K,Q) = S^T -> lane owns q = lane&31; softmax is
// in-lane (16 regs) + one shfl_xor(32). P packed to f16 in-register, fed to
// PV as A-frags. Defer-max rescale (log2 domain, THR=8).
__global__ __launch_bounds__(256, 2) void k_attn(const _Float16* __restrict__ Q,
                                                 const _Float16* __restrict__ Kt,
                                                 const _Float16* __restrict__ Vt,
                                                 _Float16* __restrict__ O) {
  extern __shared__ char lds[];
  int wg = blockIdx.x;
  int b = wg & 7, qt = wg >> 3;  // batch -> XCD pinning
  const _Float16* Qb  = Q  + (size_t)b * HWC;
  const _Float16* Ktb = Kt + (size_t)b * HWC;
  const _Float16* Vtb = Vt + (size_t)b * HWC;
  _Float16* Ob = O + (size_t)b * HWC;
  int t = threadIdx.x, wave = t >> 6, lane = t & 63;
  int lq = lane & 31, hi = lane >> 5;
  int q0 = qt * 128 + wave * 32;

  // Q frags (B-operand): row = lq (q), k = ch in 16-ch steps, hi picks 8
  half8 qf[16];
#pragma unroll
  for (int ks = 0; ks < 16; ++ks)
    qf[ks] = *reinterpret_cast<const half8*>(Qb + (size_t)(q0 + lq) * 256 + ks * 16 + hi * 8);

  f32x16 oacc[8] = {};  // O block: 32 q x 256 ch; col=lq=ch_local, row pattern=q
  float mrun = -1e30f, lrun = 0.f;

  // stage KVBLK=32 tile: K [32 keys][256ch] + V [256ch][32 keys], src pre-swizzled
#define STAGEKV(kb_, base_)                                                        \
  {                                                                                \
    _Pragma("unroll") for (int i = 0; i < 4; ++i) {                                \
      int c = i * 256 + t;                                                         \
      int key = c >> 5, co = c & 31;                                               \
      G2L(Ktb + (size_t)((kb_) * 32 + key) * 256 + ((co ^ (key & 7)) * 8),         \
          lds + (base_) + (i * 256 + wave * 64) * 16);                             \
    }                                                                              \
    _Pragma("unroll") for (int i = 0; i < 4; ++i) {                                \
      int c = i * 256 + t;                                                         \
      int ch = c >> 2, ko = c & 3;                                                 \
      G2L(Vtb + (size_t)ch * 4096 + (kb_) * 32 + ((ko ^ ((ch >> 1) & 3)) * 8),     \
          lds + (base_) + 16384 + (i * 256 + wave * 64) * 16);                     \
    }                                                                              \
  }

  STAGEKV(0, 0);
  __syncthreads();
  int cur = 0;

#pragma unroll 1
  for (int kb = 0; kb < 128; ++kb) {
    if (kb < 127) STAGEKV(kb + 1, (cur ^ 1) * 32768);  // async; lands by next barrier

    const char* Kl = lds + cur * 32768;
    const char* Vl = lds + cur * 32768 + 16384;

    // S^T = K * Q^T over 256 ch (16 k-steps). A = K frag (row=key=lq).
    f32x16 sacc = {};
#pragma unroll
    for (int ks = 0; ks < 16; ++ks) {
      half8 kf = *reinterpret_cast<const half8*>(
          Kl + ((lq * 512 + ks * 32 + hi * 16) ^ ((lq & 7) << 4)));
      sacc = __builtin_amdgcn_mfma_f32_32x32x16_f16(kf, qf[ks], sacc, 0, 0, 0);
    }

    // ---- softmax (log2 domain; lane owns q=lq; keys = (r&3)+8*(r>>2)+4*hi) ----
    float pmax = sacc[0];
#pragma unroll
    for (int r = 1; r < 16; ++r) pmax = fmaxf(pmax, sacc[r]);
    pmax = fmaxf(pmax, __shfl_xor(pmax, 32));
    if (__any(pmax > mrun + 8.0f)) {  // defer-max: rescale rarely
      float mnew = fmaxf(mrun, pmax);
      float al = exp2f(mrun - mnew);
      lrun *= al;
#pragma unroll
      for (int r = 0; r < 16; ++r) {
        float ap = __shfl(al, ((r & 3) + 8 * (r >> 2) + 4 * hi) | (lane & 32));
#pragma unroll
        for (int nt = 0; nt < 8; ++nt) oacc[nt][r] *= ap;
      }
      mrun = mnew;
    }
    float p[16], s = 0.f;
#pragma unroll
    for (int r = 0; r < 16; ++r) { p[r] = exp2f(sacc[r] - mrun); s += p[r]; }
    s += __shfl_xor(s, 32);
    lrun += s;

    // ---- pack P to f16 A-frags in-register ----
    unsigned own[8];
#pragma unroll
    for (int m = 0; m < 8; ++m)
      own[m] = __builtin_bit_cast(unsigned,
                 __builtin_amdgcn_cvt_pkrtz(p[2 * m], p[2 * m + 1]));
    unsigned prt[8];
#pragma unroll
    for (int m = 0; m < 8; ++m) prt[m] = (unsigned)__shfl_xor((int)own[m], 32);
    // frag ks=0 (keys 0-15), ks=1 (keys 16-31); own keys = pairs per hi pattern
    uint4 w0 = make_uint4(hi ? prt[2] : own[0], hi ? prt[3] : own[1],
                          hi ? own[2] : prt[0], hi ? own[3] : prt[1]);
    uint4 w1 = make_uint4(hi ? prt[6] : own[4], hi ? prt[7] : own[5],
                          hi ? own[6] : prt[4], hi ? own[7] : prt[5]);
    half8 pa0 = __builtin_bit_cast(half8, w0);
    half8 pa1 = __builtin_bit_cast(half8, w1);

    // ---- O += P @ V ; B = V frag (row=ch), k = keys ----
#pragma unroll
    for (int nt = 0; nt < 8; ++nt) {
      int ch = nt * 32 + lq;
      int sw = ((ch >> 1) & 3) << 4;
      half8 v0 = *reinterpret_cast<const half8*>(Vl + ((ch * 64 + hi * 16) ^ sw));
      oacc[nt] = __builtin_amdgcn_mfma_f32_32x32x16_f16(pa0, v0, oacc[nt], 0, 0, 0);
      half8 v1 = *reinterpret_cast<const half8*>(Vl + ((ch * 64 + 32 + hi * 16) ^ sw));
      oacc[nt] = __builtin_amdgcn_mfma_f32_32x32x16_f16(pa1, v1, oacc[nt], 0, 0, 0);
    }

    __syncthreads();  // drains vmcnt: next tile landed; cur safe to overwrite
    cur ^= 1;
  }
#undef STAGEKV

  // ---- finalize: O /= l, redistribute 1/l to the D row pattern ----
  float li = 1.0f / lrun;
#pragma unroll
  for (int r = 0; r < 16; ++r) {
    int qrow = (r & 3) + 8 * (r >> 2) + 4 * hi;
    float lv = __shfl(li, qrow | (lane & 32));
    _Float16* dst = Ob + (size_t)(q0 + qrow) * 256 + lq;
#pragma unroll
    for (int nt = 0; nt < 8; ++nt) dst[nt * 32] = (_Float16)(oacc[nt][r] * lv);
  }
}

// ---------------- launcher ----------------
// Workspace layout (MB offsets), 65 MB peak:
//   Wbf @0 (0.5MB); Xt @1..17 (-> Vtb); Qb @17..33 (-> Lb); Ktb @33..49;
//   Vc @49..65 (-> Ob)
extern "C" void kernel_launch(void* const* d_in, const int* in_sizes, int n_in,
                              void* d_out, int out_size, void* d_ws, size_t ws_size,
                              hipStream_t stream) {
  (void)in_sizes; (void)n_in; (void)out_size; (void)ws_size;
  const float* X  = (const float*)d_in[0];
  const float* Wq = (const float*)d_in[1];
  const float* Wk = (const float*)d_in[2];
  const float* Wv = (const float*)d_in[3];
  const float* Wp = (const float*)d_in[4];

  char* ws = (char*)d_ws;
  _Float16* Wbf = (_Float16*)ws;                    // 4 x 65536 f16
  _Float16* Xt  = (_Float16*)(ws + (1ull  << 20));  // (B,HW,C) f16
  _Float16* Qb  = (_Float16*)(ws + (17ull << 20));  // flat (C,HW) == view (HW,C)
  _Float16* Ktb = (_Float16*)(ws + (33ull << 20));  // (HW,C) = Kc^T
  _Float16* Vc  = (_Float16*)(ws + (49ull << 20));  // temp V flat (C,HW)
  _Float16* Vtb = Xt;                               // (C,HW) view-transpose of V
  _Float16* Ob  = Vc;                               // attn out flat (HW,C)
  _Float16* Lb  = Qb;                               // O-chw-view transposed (HW,C)

  // W -> f16
  k_convert_w<<<256, 256, 0, stream>>>(Wq, Wk, Wv, Wp, Wbf);
  // X (B,256,4096) fp32 -> Xt (B,4096,256) f16
  k_transpose_f32<<<dim3(64, 4, 8), 256, 0, stream>>>(X, Xt, 256, 4096);
  // Q = Wq @ X, scaled log2e/sqrt(256) (softmax in log2 domain), flat (256,4096)
  k_gemm<false><<<dim3(64, 4, 8), 256, 0, stream>>>(Wbf, Xt, Qb, 256, 4096, 0, HWC, HWC,
                                                    0.0625f * 1.4426950408889634f);
  // Kt[l][c] = (Wk @ X)^T, produced directly via role swap
  k_gemm<false><<<dim3(4, 64, 8), 256, 0, stream>>>(Xt, Wbf + 65536, Ktb, 4096, 256, HWC, 0, HWC, 1.0f);
  // Vc = Wv @ X flat (256,4096)
  k_gemm<false><<<dim3(64, 4, 8), 256, 0, stream>>>(Wbf + 131072, Xt, Vc, 256, 4096, 0, HWC, HWC, 1.0f);
  // Vt = transpose of V-view (4096,256) -> (256,4096)   [writes over Xt: dead]
  k_transpose_h16<<<dim3(4, 64, 8), 256, 0, stream>>>(Vc, Vtb, 4096, 256);
  // flash attention -> O flat (4096,256)                [writes over Vc: dead]
  k_attn<<<256, 256, 65536, stream>>>(Qb, Ktb, Vtb, Ob);
  // L = transpose of O-chw-view (256,4096) -> (4096,256) [writes over Qb: dead]
  k_transpose_h16<<<dim3(64, 4, 8), 256, 0, stream>>>(Ob, Lb, 256, 4096);
  // out = Wp @ O_chw, fp32
  k_gemm<true><<<dim3(64, 4, 8), 256, 0, stream>>>(Wbf + 196608, Lb, d_out, 256, 4096, 0, HWC, HWC, 1.0f);
}